// Round 1
// baseline (136.631 us; speedup 1.0000x reference)
//
#include <hip/hip_runtime.h>

// OriEmbeddingBlock: TensorProduct(1o x 1o -> 128x0e + 128x1e + 128x2e), uvw, shared weights.
// Key facts:
//  - l=1 output block is identically ZERO (antisymmetric CG contracted with v (x) v).
//  - e3nn l=1 basis order: index 0=y, 1=z, 2=x within each ori row.
//  - Output [N, 1152]: cols 0..127 = w0[col] * |v|^2/sqrt(3)
//                      cols 128..511 = 0
//                      cols 512..1151: j=col-512, w2[j/5] * s2[j%5]
//    s2 = [sqrt(2)xy, sqrt(2)yz, sqrt(1/6)(2z^2-x^2-y^2), sqrt(2)zx, sqrt(1/2)(x^2-y^2)]
// Memory-bound: 460.8 MB of fp32 writes dominate.

#define THREADS 256
#define CHUNKS 288   // 1152 cols / 4 per float4
#define GRID 1152    // multiple of 9 so GRID*256 is a multiple of 288

__global__ __launch_bounds__(THREADS) void ori_embed_kernel(
    const float* __restrict__ ori,
    const float* __restrict__ weights,
    float* __restrict__ out,
    int n_rows)
{
    const int tid = blockIdx.x * THREADS + threadIdx.x;
    const int total = gridDim.x * THREADS;
    const int c = tid % CHUNKS;            // loop-invariant chunk within row
    int n = tid / CHUNKS;                  // starting row
    const int nstride = total / CHUNKS;    // 1024

    // Per-thread setup: 4 columns col = 4c+i -> (coef, selector)
    float coef[4];
    int sel[4];  // 0 -> t0s, 1..5 -> s2[sel-1]
#pragma unroll
    for (int i = 0; i < 4; ++i) {
        int col = 4 * c + i;
        if (col < 128) {
            coef[i] = weights[col];
            sel[i] = 0;
        } else if (col < 512) {
            coef[i] = 0.0f;       // l=1 block is identically zero
            sel[i] = 0;
        } else {
            int j = col - 512;
            coef[i] = weights[256 + j / 5];
            sel[i] = 1 + (j % 5);
        }
    }

    const float inv_sqrt3   = 0.57735026918962576f;  // 1/sqrt(3)
    const float c_xy        = 1.41421356237309505f;  // sqrt(5)*2a = sqrt(2)
    const float c_x2y2      = 0.70710678118654752f;  // sqrt(5)*a  = sqrt(1/2)
    const float c_z2        = 0.40824829046386302f;  // sqrt(5)*a/sqrt(3) = sqrt(1/6)

    float4* __restrict__ out4 = reinterpret_cast<float4*>(out);

    for (; n < n_rows; n += nstride) {
        const float vy = ori[3 * n + 0];   // e3nn index 0 = y
        const float vz = ori[3 * n + 1];   // index 1 = z
        const float vx = ori[3 * n + 2];   // index 2 = x

        const float xx = vx * vx, yy = vy * vy, zz = vz * vz;
        const float t0s = (xx + yy + zz) * inv_sqrt3;
        const float s2_0 = c_xy * vx * vy;               // k=0: xy
        const float s2_1 = c_xy * vy * vz;               // k=1: yz
        const float s2_2 = c_z2 * (2.0f * zz - xx - yy); // k=2
        const float s2_3 = c_xy * vz * vx;               // k=3: zx
        const float s2_4 = c_x2y2 * (xx - yy);           // k=4

        float r[4];
#pragma unroll
        for (int i = 0; i < 4; ++i) {
            // sel[i] is loop-invariant -> v_cmp hoisted, 5 cndmask per col
            float t = t0s;
            t = (sel[i] == 1) ? s2_0 : t;
            t = (sel[i] == 2) ? s2_1 : t;
            t = (sel[i] == 3) ? s2_2 : t;
            t = (sel[i] == 4) ? s2_3 : t;
            t = (sel[i] == 5) ? s2_4 : t;
            r[i] = coef[i] * t;
        }
        out4[(size_t)n * CHUNKS + c] = make_float4(r[0], r[1], r[2], r[3]);
    }
}

extern "C" void kernel_launch(void* const* d_in, const int* in_sizes, int n_in,
                              void* d_out, int out_size, void* d_ws, size_t ws_size,
                              hipStream_t stream) {
    const float* ori = (const float*)d_in[0];
    const float* weights = (const float*)d_in[1];
    float* out = (float*)d_out;
    const int n_rows = in_sizes[0] / 3;

    hipLaunchKernelGGL(ori_embed_kernel, dim3(GRID), dim3(THREADS), 0, stream,
                       ori, weights, out, n_rows);
}

// Round 2
// 114.084 us; speedup vs baseline: 1.1976x; 1.1976x over previous
//
#include <hip/hip_runtime.h>

// OriEmbeddingBlock: TensorProduct(1o x 1o -> 128x0e + 128x1e + 128x2e), uvw, shared weights.
//  - l=1 output block (cols 128..511) is identically ZERO (antisymmetric CG vs v(x)v).
//  - e3nn l=1 basis order within an ori row: 0=y, 1=z, 2=x.
//  - cols 0..127:   w0[col] * |v|^2 / sqrt(3)
//  - cols 512..1151: j=col-512, w2[j/5] * s2[j%5],
//    s2 = [sqrt(2)xy, sqrt(2)yz, sqrt(1/6)(2z^2-x^2-y^2), sqrt(2)zx, sqrt(1/2)(x^2-y^2)]
// Pure write-stream problem: 460.8 MB fp32 out. v2: 32B/thread/row + 2-row unroll
// + 2304-block grid to raise memory-level parallelism per wave.

#define THREADS 256
#define CPR 144                      // 32B chunks per row (1152 cols / 8)
#define GRID 2304                    // GRID*THREADS = 589824 = 4096 rows * 144
#define SWEEP ((GRID * THREADS) / CPR)  // 4096 rows per sweep

struct RowS { float s0, s1, s2, s3, s4, s5; };

__device__ __forceinline__ RowS row_s(const float* __restrict__ ori, int n) {
    const float vy = ori[3 * n + 0];   // e3nn index 0 = y
    const float vz = ori[3 * n + 1];   // index 1 = z
    const float vx = ori[3 * n + 2];   // index 2 = x
    const float xx = vx * vx, yy = vy * vy, zz = vz * vz;
    RowS r;
    r.s0 = (xx + yy + zz) * 0.57735026918962576f;   // |v|^2/sqrt(3)
    r.s1 = 1.41421356237309505f * (vx * vy);        // sqrt(2) xy
    r.s2 = 1.41421356237309505f * (vy * vz);        // sqrt(2) yz
    r.s3 = 0.40824829046386302f * (2.0f * zz - xx - yy); // sqrt(1/6)(2z^2-x^2-y^2)
    r.s4 = 1.41421356237309505f * (vz * vx);        // sqrt(2) zx
    r.s5 = 0.70710678118654752f * (xx - yy);        // sqrt(1/2)(x^2-y^2)
    return r;
}

__device__ __forceinline__ void emit(float4* __restrict__ out4, size_t base,
                                     const RowS& v,
                                     const float coef[8], const int sel[8]) {
    float r[8];
#pragma unroll
    for (int i = 0; i < 8; ++i) {
        // sel[i] loop-invariant -> cmps hoisted/cheap; 5 cndmask per col
        float t = v.s0;
        t = (sel[i] == 1) ? v.s1 : t;
        t = (sel[i] == 2) ? v.s2 : t;
        t = (sel[i] == 3) ? v.s3 : t;
        t = (sel[i] == 4) ? v.s4 : t;
        t = (sel[i] == 5) ? v.s5 : t;
        r[i] = coef[i] * t;
    }
    out4[base]     = make_float4(r[0], r[1], r[2], r[3]);
    out4[base + 1] = make_float4(r[4], r[5], r[6], r[7]);
}

__global__ __launch_bounds__(THREADS) void ori_embed_kernel(
    const float* __restrict__ ori,
    const float* __restrict__ weights,
    float* __restrict__ out,
    int n_rows)
{
    const int tid = blockIdx.x * THREADS + threadIdx.x;
    const int c = tid % CPR;        // loop-invariant 32B chunk within row
    const int n0 = tid / CPR;

    // Per-thread setup: 8 columns col = 8c+i -> (coef, selector).
    // Chunks never straddle region boundaries (128/8=16, 512/8=64).
    float coef[8];
    int sel[8];   // 0 -> s0, 1..5 -> s2 components
#pragma unroll
    for (int i = 0; i < 8; ++i) {
        const int col = 8 * c + i;
        if (col < 128)      { coef[i] = weights[col];           sel[i] = 0; }
        else if (col < 512) { coef[i] = 0.0f;                   sel[i] = 0; }
        else { const int j = col - 512;
               coef[i] = weights[256 + j / 5];                  sel[i] = 1 + j % 5; }
    }

    float4* __restrict__ out4 = reinterpret_cast<float4*>(out);

    int n = n0;
    for (; n + SWEEP < n_rows; n += 2 * SWEEP) {
        // issue both rows' loads up front (independent), then compute+store both
        RowS a = row_s(ori, n);
        RowS b = row_s(ori, n + SWEEP);
        emit(out4, (size_t)n * (2 * CPR) + 2 * c, a, coef, sel);
        emit(out4, (size_t)(n + SWEEP) * (2 * CPR) + 2 * c, b, coef, sel);
    }
    if (n < n_rows) {
        RowS a = row_s(ori, n);
        emit(out4, (size_t)n * (2 * CPR) + 2 * c, a, coef, sel);
    }
}

extern "C" void kernel_launch(void* const* d_in, const int* in_sizes, int n_in,
                              void* d_out, int out_size, void* d_ws, size_t ws_size,
                              hipStream_t stream) {
    const float* ori = (const float*)d_in[0];
    const float* weights = (const float*)d_in[1];
    float* out = (float*)d_out;
    const int n_rows = in_sizes[0] / 3;

    hipLaunchKernelGGL(ori_embed_kernel, dim3(GRID), dim3(THREADS), 0, stream,
                       ori, weights, out, n_rows);
}

// Round 3
// 98.705 us; speedup vs baseline: 1.3842x; 1.1558x over previous
//
#include <hip/hip_runtime.h>

// OriEmbeddingBlock: TensorProduct(1o x 1o -> 128x0e + 128x1e + 128x2e), uvw, shared weights.
//  - l=1 output block (cols 128..511) is identically ZERO (antisymmetric CG vs v(x)v).
//  - e3nn l=1 basis order within an ori row: 0=y, 1=z, 2=x.
//  - cols 0..127:   w0[col] * |v|^2 / sqrt(3)
//  - cols 512..1151: j=col-512, w2[j/5] * s2[j%5],
//    s2 = [sqrt(2)xy, sqrt(2)yz, sqrt(1/6)(2z^2-x^2-y^2), sqrt(2)zx, sqrt(1/2)(x^2-y^2)]
// Pure write-stream problem: 460.8 MB fp32 out.
// v3: fully-coalesced stores (thread owns chunks c and c+144 of the 288-chunk row,
//     so every wave store is a contiguous 1KB burst — v2's 32B-stride pattern halved
//     store efficiency), plus explicit load-before-store software pipeline.

#define THREADS 256
#define CPR 144                      // threads per row; row = 288 float4 chunks
#define GRID 2016                    // multiple of 9 -> GRID*256 divisible by 144; ~7.9 blocks/CU
#define SWEEP ((GRID * THREADS) / CPR)  // 3584 rows per sweep

struct RowS { float s0, s1, s2, s3, s4, s5; };

__device__ __forceinline__ RowS row_s(const float* __restrict__ ori, int n) {
    const float vy = ori[3 * n + 0];   // e3nn index 0 = y
    const float vz = ori[3 * n + 1];   // index 1 = z
    const float vx = ori[3 * n + 2];   // index 2 = x
    const float xx = vx * vx, yy = vy * vy, zz = vz * vz;
    RowS r;
    r.s0 = (xx + yy + zz) * 0.57735026918962576f;        // |v|^2/sqrt(3)
    r.s1 = 1.41421356237309505f * (vx * vy);             // sqrt(2) xy
    r.s2 = 1.41421356237309505f * (vy * vz);             // sqrt(2) yz
    r.s3 = 0.40824829046386302f * (2.0f * zz - xx - yy); // sqrt(1/6)(2z^2-x^2-y^2)
    r.s4 = 1.41421356237309505f * (vz * vx);             // sqrt(2) zx
    r.s5 = 0.70710678118654752f * (xx - yy);             // sqrt(1/2)(x^2-y^2)
    return r;
}

__device__ __forceinline__ void emit(float4* __restrict__ out4, int n, int c,
                                     const RowS& v,
                                     const float coef[8], const int sel[8]) {
    float r[8];
#pragma unroll
    for (int i = 0; i < 8; ++i) {
        float t = v.s0;
        t = (sel[i] == 1) ? v.s1 : t;
        t = (sel[i] == 2) ? v.s2 : t;
        t = (sel[i] == 3) ? v.s3 : t;
        t = (sel[i] == 4) ? v.s4 : t;
        t = (sel[i] == 5) ? v.s5 : t;
        r[i] = coef[i] * t;
    }
    const size_t base = (size_t)n * (2 * CPR) + c;
    out4[base]       = make_float4(r[0], r[1], r[2], r[3]);  // chunk c       (lane-contiguous)
    out4[base + CPR] = make_float4(r[4], r[5], r[6], r[7]);  // chunk c+144   (lane-contiguous)
}

__global__ __launch_bounds__(THREADS) void ori_embed_kernel(
    const float* __restrict__ ori,
    const float* __restrict__ weights,
    float* __restrict__ out,
    int n_rows)
{
    const int tid = blockIdx.x * THREADS + threadIdx.x;
    const int c = tid % CPR;        // loop-invariant chunk within row
    const int n0 = tid / CPR;

    // Columns owned: chunk A = cols 4c..4c+3, chunk B = cols 576+4c..576+4c+3.
    float coef[8];
    int sel[8];   // 0 -> s0, 1..5 -> l2 components
#pragma unroll
    for (int i = 0; i < 8; ++i) {
        const int col = (i < 4) ? (4 * c + i) : (576 + 4 * c + (i - 4));
        if (col < 128)      { coef[i] = weights[col];  sel[i] = 0; }
        else if (col < 512) { coef[i] = 0.0f;          sel[i] = 0; }
        else { const int j = col - 512;
               coef[i] = weights[256 + j / 5];         sel[i] = 1 + j % 5; }
    }

    float4* __restrict__ out4 = reinterpret_cast<float4*>(out);

    int n = n0;
    if (n + SWEEP < n_rows) {
        RowS a = row_s(ori, n);
        RowS b = row_s(ori, n + SWEEP);
        for (;;) {
            const int nn = n + 2 * SWEEP;
            const bool more = nn + SWEEP < n_rows;
            RowS na, nb;
            if (more) {                 // prefetch next pair BEFORE this pair's stores
                na = row_s(ori, nn);
                nb = row_s(ori, nn + SWEEP);
            }
            emit(out4, n, c, a, coef, sel);
            emit(out4, n + SWEEP, c, b, coef, sel);
            n = nn;
            if (!more) break;
            a = na; b = nb;
        }
    }
    if (n < n_rows) {
        RowS a = row_s(ori, n);
        emit(out4, n, c, a, coef, sel);
    }
}

extern "C" void kernel_launch(void* const* d_in, const int* in_sizes, int n_in,
                              void* d_out, int out_size, void* d_ws, size_t ws_size,
                              hipStream_t stream) {
    const float* ori = (const float*)d_in[0];
    const float* weights = (const float*)d_in[1];
    float* out = (float*)d_out;
    const int n_rows = in_sizes[0] / 3;

    hipLaunchKernelGGL(ori_embed_kernel, dim3(GRID), dim3(THREADS), 0, stream,
                       ori, weights, out, n_rows);
}

// Round 4
// 93.556 us; speedup vs baseline: 1.4604x; 1.0550x over previous
//
#include <hip/hip_runtime.h>

// OriEmbeddingBlock: TensorProduct(1o x 1o -> 128x0e + 128x1e + 128x2e), uvw, shared weights.
//  - l=1 output block (cols 128..511) is identically ZERO (antisymmetric CG vs v(x)v).
//  - e3nn l=1 basis order within an ori row: 0=y, 1=z, 2=x.
//  - cols 0..127:   w0[col] * |v|^2 / sqrt(3)
//  - cols 512..1151: j=col-512, w2[j/5] * s2[j%5],
//    s2 = [sqrt(2)xy, sqrt(2)yz, sqrt(1/6)(2z^2-x^2-y^2), sqrt(2)zx, sqrt(1/2)(x^2-y^2)]
// Pure write-stream problem: 460.8 MB fp32 out.
// v4: preload-then-stream. Each thread owns 28 CONSECUTIVE rows x 1 chunk-pair:
//     21x global_load_dwordx4 up front (336B contiguous, aligned), ONE waitcnt,
//     then 56 back-to-back global_store_dwordx4 with no intervening waits --
//     matching the fill kernel's never-wait store stream (6.9 TB/s at 11% occ).

#define THREADS 256
#define CPR 144                         // threads per row; row = 288 float4 chunks
#define GRID 2016                       // GRID*THREADS = 516096 = 3584 groups * 144
#define RPT 28                          // rows per thread (3584*28 = 100352 >= 100000)

__global__ __launch_bounds__(THREADS) void ori_embed_kernel(
    const float* __restrict__ ori,
    const float* __restrict__ weights,
    float* __restrict__ out,
    int n_rows)
{
    const int tid = blockIdx.x * THREADS + threadIdx.x;
    const int c = tid % CPR;            // chunk within row (owns chunks c and c+144)
    const int g = tid / CPR;            // row group
    const int r0 = g * RPT;

    // Columns owned: chunk A = cols 4c..4c+3, chunk B = cols 576+4c..576+4c+3.
    float coef[8];
    int sel[8];   // 0 -> s0 (l=0 value), 1..5 -> l=2 components
#pragma unroll
    for (int i = 0; i < 8; ++i) {
        const int col = (i < 4) ? (4 * c + i) : (576 + 4 * c + (i - 4));
        if (col < 128)      { coef[i] = weights[col];  sel[i] = 0; }
        else if (col < 512) { coef[i] = 0.0f;          sel[i] = 0; }
        else { const int j = col - 512;
               coef[i] = weights[256 + j / 5];         sel[i] = 1 + j % 5; }
    }

    float4* __restrict__ out4 = reinterpret_cast<float4*>(out);

    if (r0 + RPT <= n_rows) {
        // ---- fast path: preload all 28 rows (84 floats = 21 float4, 16B-aligned
        //      since 12*r0 = 336*g is a multiple of 16), then stream 56 stores ----
        union { float4 v[RPT * 3 / 4]; float f[RPT * 3]; } d;
        const float4* __restrict__ src =
            reinterpret_cast<const float4*>(ori + 3 * (size_t)r0);
#pragma unroll
        for (int k = 0; k < RPT * 3 / 4; ++k) d.v[k] = src[k];

#pragma unroll
        for (int j = 0; j < RPT; ++j) {
            const float vy = d.f[3 * j + 0];   // e3nn 0 = y
            const float vz = d.f[3 * j + 1];   // 1 = z
            const float vx = d.f[3 * j + 2];   // 2 = x
            const float xx = vx * vx, yy = vy * vy, zz = vz * vz;
            const float s0 = (xx + yy + zz) * 0.57735026918962576f;
            const float s1 = 1.41421356237309505f * (vx * vy);
            const float s2 = 1.41421356237309505f * (vy * vz);
            const float s3 = 0.40824829046386302f * (2.0f * zz - xx - yy);
            const float s4 = 1.41421356237309505f * (vz * vx);
            const float s5 = 0.70710678118654752f * (xx - yy);

            float r[8];
#pragma unroll
            for (int i = 0; i < 8; ++i) {
                float t = s0;
                t = (sel[i] == 1) ? s1 : t;
                t = (sel[i] == 2) ? s2 : t;
                t = (sel[i] == 3) ? s3 : t;
                t = (sel[i] == 4) ? s4 : t;
                t = (sel[i] == 5) ? s5 : t;
                r[i] = coef[i] * t;
            }
            const size_t base = (size_t)(r0 + j) * (2 * CPR) + c;
            out4[base]       = make_float4(r[0], r[1], r[2], r[3]);
            out4[base + CPR] = make_float4(r[4], r[5], r[6], r[7]);
        }
    } else {
        // ---- tail path (one partial group; a few idle groups past the end) ----
        for (int j = 0; r0 + j < n_rows; ++j) {
            const int n = r0 + j;
            const float vy = ori[3 * n + 0];
            const float vz = ori[3 * n + 1];
            const float vx = ori[3 * n + 2];
            const float xx = vx * vx, yy = vy * vy, zz = vz * vz;
            const float s0 = (xx + yy + zz) * 0.57735026918962576f;
            const float s1 = 1.41421356237309505f * (vx * vy);
            const float s2 = 1.41421356237309505f * (vy * vz);
            const float s3 = 0.40824829046386302f * (2.0f * zz - xx - yy);
            const float s4 = 1.41421356237309505f * (vz * vx);
            const float s5 = 0.70710678118654752f * (xx - yy);

            float r[8];
#pragma unroll
            for (int i = 0; i < 8; ++i) {
                float t = s0;
                t = (sel[i] == 1) ? s1 : t;
                t = (sel[i] == 2) ? s2 : t;
                t = (sel[i] == 3) ? s3 : t;
                t = (sel[i] == 4) ? s4 : t;
                t = (sel[i] == 5) ? s5 : t;
                r[i] = coef[i] * t;
            }
            const size_t base = (size_t)n * (2 * CPR) + c;
            out4[base]       = make_float4(r[0], r[1], r[2], r[3]);
            out4[base + CPR] = make_float4(r[4], r[5], r[6], r[7]);
        }
    }
}

extern "C" void kernel_launch(void* const* d_in, const int* in_sizes, int n_in,
                              void* d_out, int out_size, void* d_ws, size_t ws_size,
                              hipStream_t stream) {
    const float* ori = (const float*)d_in[0];
    const float* weights = (const float*)d_in[1];
    float* out = (float*)d_out;
    const int n_rows = in_sizes[0] / 3;

    hipLaunchKernelGGL(ori_embed_kernel, dim3(GRID), dim3(THREADS), 0, stream,
                       ori, weights, out, n_rows);
}